// Round 6
// baseline (186.864 us; speedup 1.0000x reference)
//
#include <hip/hip_runtime.h>
#include <hip/hip_bf16.h>
#include <stdint.h>

#define M_DIM 2048
#define N_DIM 4096
#define K_DIM 4096

#define BM 128
#define BN 256
#define BK 64

typedef __bf16 bf16x8 __attribute__((ext_vector_type(8)));
typedef float f32x4 __attribute__((ext_vector_type(4)));
typedef unsigned short ushort8_t __attribute__((ext_vector_type(8)));

__device__ __forceinline__ unsigned short f32_to_bf16_rne(float f) {
    union { float f; uint32_t u; } cvt;
    cvt.f = f;
    uint32_t u = cvt.u;
    uint32_t r = (u + 0x7fffu + ((u >> 16) & 1u)) >> 16;
    return (unsigned short)r;
}

__device__ __forceinline__ void gload_lds16(const void* g, void* l) {
    __builtin_amdgcn_global_load_lds(
        (__attribute__((address_space(1))) const void*)g,
        (__attribute__((address_space(3))) void*)l,
        16, 0, 0);
}

// ---------------------------------------------------------------------------
// x (f32 [M][K]) -> bf16 [M][K]
// ---------------------------------------------------------------------------
__global__ void convert_x_kernel(const float* __restrict__ x,
                                 unsigned short* __restrict__ xb, int n8) {
    int i = blockIdx.x * blockDim.x + threadIdx.x;
    int stride = gridDim.x * blockDim.x;
    for (; i < n8; i += stride) {
        const float4* p = (const float4*)(x + (size_t)i * 8);
        float4 v0 = p[0];
        float4 v1 = p[1];
        ushort8_t o;
        o[0] = f32_to_bf16_rne(v0.x);
        o[1] = f32_to_bf16_rne(v0.y);
        o[2] = f32_to_bf16_rne(v0.z);
        o[3] = f32_to_bf16_rne(v0.w);
        o[4] = f32_to_bf16_rne(v1.x);
        o[5] = f32_to_bf16_rne(v1.y);
        o[6] = f32_to_bf16_rne(v1.z);
        o[7] = f32_to_bf16_rne(v1.w);
        *(ushort8_t*)(xb + (size_t)i * 8) = o;
    }
}

// ---------------------------------------------------------------------------
// W (f32 [K][N]) -> Wt (bf16 [N][K])   tiled 64x64 transpose+convert
// ---------------------------------------------------------------------------
__global__ void transpose_convert_w(const float* __restrict__ W,
                                    unsigned short* __restrict__ Wt) {
    __shared__ float tile[64][65];
    const int k0 = blockIdx.y * 64;
    const int n0 = blockIdx.x * 64;
    const int t  = threadIdx.x;
    const int tx = t & 15;
    const int ty = t >> 4;

#pragma unroll
    for (int r = 0; r < 4; ++r) {
        int row = ty + 16 * r;
        float4 v = *(const float4*)(W + (size_t)(k0 + row) * N_DIM + n0 + tx * 4);
        tile[row][tx * 4 + 0] = v.x;
        tile[row][tx * 4 + 1] = v.y;
        tile[row][tx * 4 + 2] = v.z;
        tile[row][tx * 4 + 3] = v.w;
    }
    __syncthreads();
#pragma unroll
    for (int r = 0; r < 4; ++r) {
        int nrow = ty + 16 * r;
        ushort4 o;
        o.x = f32_to_bf16_rne(tile[tx * 4 + 0][nrow]);
        o.y = f32_to_bf16_rne(tile[tx * 4 + 1][nrow]);
        o.z = f32_to_bf16_rne(tile[tx * 4 + 2][nrow]);
        o.w = f32_to_bf16_rne(tile[tx * 4 + 3][nrow]);
        *(ushort4*)(Wt + (size_t)(n0 + nrow) * K_DIM + k0 + tx * 4) = o;
    }
}

// ---------------------------------------------------------------------------
// GEMM: C[m][n] = sum_k A[m][k] * Bt[n][k] + bias[n]
// R3 skeleton for B (triple-buffered LDS, ONE vmcnt+barrier per K-tile,
// proven 0-conflict 16-row x 4-slotgroup swizzle, 16x16x32 MFMA, setprio,
// free compiler scheduling inside the tile region).
// NEW: A-operand bypasses LDS -> global到VGPR, double-buffered one tile
// ahead (plain loads; compiler tracks the register dependency). 4 waves
// share identical A-frags -> L1-served after first wave. LDS reads/tile
// drop 128KB -> 64KB (below the 1242-cyc MFMA floor); LDS = 96 KiB.
// Manual vmcnt(4) covers only the B gload_lds RAW (safe under any
// intra-region issue order); lgkmcnt(0)+barrier covers B-buffer WAR.
// ---------------------------------------------------------------------------
__global__ __launch_bounds__(512, 2) void gemm_bf16(
    const unsigned short* __restrict__ A,
    const unsigned short* __restrict__ Bt,
    const float* __restrict__ bias,
    float* __restrict__ C) {
    __shared__ unsigned short sB[3][BN * BK];  // 3 x 32 KiB

    const int t    = threadIdx.x;
    const int lane = t & 63;
    const int wave = t >> 6;
    const int wm   = wave >> 2;  // 0..1
    const int wn   = wave & 3;   // 0..3
    const int lrow = lane & 15;
    const int lhi  = lane >> 4;

    // T1: XCD-aware swizzle (256 WGs, %8==0 -> bijective)
    const int wg  = blockIdx.x;
    const int swz = (wg & 7) * 32 + (wg >> 3);
    const int m0  = (swz >> 4) * BM;
    const int n0  = (swz & 15) * BN;

    // ---- B staging pointers (inverse-swizzled global source, linear LDS) ----
    const int rowc = t >> 3;                    // 0..63
    const int lc   = (t & 7) ^ (rowc & 7);      // swizzled k-slot
    const unsigned short* gB0 = Bt + (size_t)(n0 + rowc) * K_DIM + lc * 8;
    const unsigned short* gB1 = gB0 + (size_t)64  * K_DIM;
    const unsigned short* gB2 = gB0 + (size_t)128 * K_DIM;
    const unsigned short* gB3 = gB0 + (size_t)192 * K_DIM;
    const int dB0 = t * 16, dB1 = t * 16 + 8192,
              dB2 = t * 16 + 16384, dB3 = t * 16 + 24576;

    // ---- A fragment pointers: lane l needs row = m0+wm*64+mi*16+lrow,
    //      k = tile*64 + kk*32 + lhi*8 .. +7  (16B aligned) ----
    const unsigned short* pA[4];
#pragma unroll
    for (int mi = 0; mi < 4; ++mi)
        pA[mi] = A + (size_t)(m0 + wm * 64 + mi * 16 + lrow) * K_DIM + lhi * 8;

    f32x4 acc[4][4];
#pragma unroll
    for (int i = 0; i < 4; ++i)
#pragma unroll
        for (int j = 0; j < 4; ++j) acc[i][j] = (f32x4)0.0f;

    const int NT = K_DIM / BK;  // 64

    // per-thread B fragment offsets (row&7 == lrow&7)
    const int rowOffB = (wn * 64 + lrow) * 128;  // bytes; + nj*2048
    const int s0 = ((0 * 4 + lhi) ^ (lrow & 7)) * 16;  // kk=0 slot bytes
    const int s1 = ((1 * 4 + lhi) ^ (lrow & 7)) * 16;  // kk=1 slot bytes

    bf16x8 Aa[2][4], Ab[2][4];

    // prologue: A(0) regs first, then B(0), B(1) staged
#pragma unroll
    for (int kk = 0; kk < 2; ++kk)
#pragma unroll
        for (int mi = 0; mi < 4; ++mi)
            Aa[kk][mi] = *(const bf16x8*)(pA[mi] + kk * 32);
    {
        char* wB = (char*)sB[0];
        gload_lds16(gB0, wB + dB0); gload_lds16(gB1, wB + dB1);
        gload_lds16(gB2, wB + dB2); gload_lds16(gB3, wB + dB3);
        wB = (char*)sB[1];
        gload_lds16(gB0 + BK, wB + dB0); gload_lds16(gB1 + BK, wB + dB1);
        gload_lds16(gB2 + BK, wB + dB2); gload_lds16(gB3 + BK, wB + dB3);
    }

    // body: consume tile tau (A in Au, B in sB[tau%3]);
    //       load A(tau+1) -> Al; stage B(tau+2) -> sB[(tau+2)%3]
    auto body = [&](int tau, bf16x8 (&Au)[2][4], bf16x8 (&Al)[2][4]) {
        const size_t kA = (size_t)((tau + 1 < NT) ? tau + 1 : NT - 1) * BK;
        const size_t kB = (size_t)((tau + 2 < NT) ? tau + 2 : NT - 1) * BK;
        const int bufC = tau % 3;
        const int bufS = (tau + 2) % 3;

        // one wait + one barrier per K-tile; vmcnt NEVER drains to 0
        asm volatile("s_waitcnt vmcnt(4) lgkmcnt(0)" ::: "memory");
        __builtin_amdgcn_s_barrier();
        __builtin_amdgcn_sched_barrier(0);

        const char* bB = (const char*)sB[bufC];

        // B fragments from LDS (proven 0-conflict pattern)
        bf16x8 bf[2][4];
#pragma unroll
        for (int nj = 0; nj < 4; ++nj) {
            bf[0][nj] = *(const bf16x8*)(bB + rowOffB + nj * 2048 + s0);
            bf[1][nj] = *(const bf16x8*)(bB + rowOffB + nj * 2048 + s1);
        }

        // A(tau+1) global -> regs (compiler inserts the dependent waits)
#pragma unroll
        for (int kk = 0; kk < 2; ++kk)
#pragma unroll
            for (int mi = 0; mi < 4; ++mi)
                Al[kk][mi] = *(const bf16x8*)(pA[mi] + kA + kk * 32);

        // B(tau+2) staging
        char* wB = (char*)sB[bufS];
        gload_lds16(gB0 + kB, wB + dB0);
        gload_lds16(gB1 + kB, wB + dB1);
        gload_lds16(gB2 + kB, wB + dB2);
        gload_lds16(gB3 + kB, wB + dB3);

        __builtin_amdgcn_s_setprio(1);
#pragma unroll
        for (int kk = 0; kk < 2; ++kk)
#pragma unroll
            for (int mi = 0; mi < 4; ++mi)
#pragma unroll
                for (int nj = 0; nj < 4; ++nj)
                    acc[mi][nj] = __builtin_amdgcn_mfma_f32_16x16x32_bf16(
                        Au[kk][mi], bf[kk][nj], acc[mi][nj], 0, 0, 0);
        __builtin_amdgcn_s_setprio(0);
    };

    for (int tau = 0; tau < NT; tau += 2) {
        body(tau, Aa, Ab);
        body(tau + 1, Ab, Aa);
    }

    // epilogue: C/D layout col=lane&15, row=(lane>>4)*4+reg
#pragma unroll
    for (int nj = 0; nj < 4; ++nj) {
        int col  = n0 + wn * 64 + nj * 16 + lrow;
        float bv = bias[col];
#pragma unroll
        for (int mi = 0; mi < 4; ++mi) {
            int rbase = m0 + wm * 64 + mi * 16 + lhi * 4;
#pragma unroll
            for (int r = 0; r < 4; ++r) {
                C[(size_t)(rbase + r) * N_DIM + col] = acc[mi][nj][r] + bv;
            }
        }
    }
}

// ---------------------------------------------------------------------------
extern "C" void kernel_launch(void* const* d_in, const int* in_sizes, int n_in,
                              void* d_out, int out_size, void* d_ws, size_t ws_size,
                              hipStream_t stream) {
    const float* x    = (const float*)d_in[0];
    const float* w    = (const float*)d_in[1];
    const float* bias = (const float*)d_in[2];
    float* out        = (float*)d_out;

    unsigned short* xb = (unsigned short*)d_ws;
    unsigned short* wt = (unsigned short*)((char*)d_ws +
                          (size_t)M_DIM * K_DIM * sizeof(unsigned short));

    convert_x_kernel<<<2048, 256, 0, stream>>>(x, xb, M_DIM * K_DIM / 8);

    dim3 tgrid(N_DIM / 64, K_DIM / 64);
    transpose_convert_w<<<tgrid, 256, 0, stream>>>(w, wt);

    dim3 ggrid((M_DIM / BM) * (N_DIM / BN));
    gemm_bf16<<<ggrid, 512, 0, stream>>>(xb, wt, bias, out);
}

// Round 7
// 95.899 us; speedup vs baseline: 1.9486x; 1.9486x over previous
//
#include <hip/hip_runtime.h>
#include <hip/hip_bf16.h>
#include <stdint.h>

#define M_DIM 2048
#define N_DIM 4096
#define K_DIM 4096

#define BM 128
#define BN 256
#define BK 64

typedef __bf16 bf16x8 __attribute__((ext_vector_type(8)));
typedef float f32x4 __attribute__((ext_vector_type(4)));
typedef unsigned short ushort8_t __attribute__((ext_vector_type(8)));

__device__ __forceinline__ unsigned short f32_to_bf16_rne(float f) {
    union { float f; uint32_t u; } cvt;
    cvt.f = f;
    uint32_t u = cvt.u;
    uint32_t r = (u + 0x7fffu + ((u >> 16) & 1u)) >> 16;
    return (unsigned short)r;
}

__device__ __forceinline__ void gload_lds16(const void* g, void* l) {
    __builtin_amdgcn_global_load_lds(
        (__attribute__((address_space(1))) const void*)g,
        (__attribute__((address_space(3))) void*)l,
        16, 0, 0);
}

// ---------------------------------------------------------------------------
// x (f32 [M][K]) -> bf16 [M][K]
// ---------------------------------------------------------------------------
__global__ void convert_x_kernel(const float* __restrict__ x,
                                 unsigned short* __restrict__ xb, int n8) {
    int i = blockIdx.x * blockDim.x + threadIdx.x;
    int stride = gridDim.x * blockDim.x;
    for (; i < n8; i += stride) {
        const float4* p = (const float4*)(x + (size_t)i * 8);
        float4 v0 = p[0];
        float4 v1 = p[1];
        ushort8_t o;
        o[0] = f32_to_bf16_rne(v0.x);
        o[1] = f32_to_bf16_rne(v0.y);
        o[2] = f32_to_bf16_rne(v0.z);
        o[3] = f32_to_bf16_rne(v0.w);
        o[4] = f32_to_bf16_rne(v1.x);
        o[5] = f32_to_bf16_rne(v1.y);
        o[6] = f32_to_bf16_rne(v1.z);
        o[7] = f32_to_bf16_rne(v1.w);
        *(ushort8_t*)(xb + (size_t)i * 8) = o;
    }
}

// ---------------------------------------------------------------------------
// W (f32 [K][N]) -> Wt (bf16 [N][K])   tiled 64x64 transpose+convert
// ---------------------------------------------------------------------------
__global__ void transpose_convert_w(const float* __restrict__ W,
                                    unsigned short* __restrict__ Wt) {
    __shared__ float tile[64][65];
    const int k0 = blockIdx.y * 64;
    const int n0 = blockIdx.x * 64;
    const int t  = threadIdx.x;
    const int tx = t & 15;
    const int ty = t >> 4;

#pragma unroll
    for (int r = 0; r < 4; ++r) {
        int row = ty + 16 * r;
        float4 v = *(const float4*)(W + (size_t)(k0 + row) * N_DIM + n0 + tx * 4);
        tile[row][tx * 4 + 0] = v.x;
        tile[row][tx * 4 + 1] = v.y;
        tile[row][tx * 4 + 2] = v.z;
        tile[row][tx * 4 + 3] = v.w;
    }
    __syncthreads();
#pragma unroll
    for (int r = 0; r < 4; ++r) {
        int nrow = ty + 16 * r;
        ushort4 o;
        o.x = f32_to_bf16_rne(tile[tx * 4 + 0][nrow]);
        o.y = f32_to_bf16_rne(tile[tx * 4 + 1][nrow]);
        o.z = f32_to_bf16_rne(tile[tx * 4 + 2][nrow]);
        o.w = f32_to_bf16_rne(tile[tx * 4 + 3][nrow]);
        *(ushort4*)(Wt + (size_t)(n0 + nrow) * K_DIM + k0 + tx * 4) = o;
    }
}

// ---------------------------------------------------------------------------
// GEMM: C[m][n] = sum_k A[m][k] * Bt[n][k] + bias[n]
// m201 8-phase schedule ported to 128x256/BK=64 (grid fills 256 CUs):
//   per K-tile = 2 phases (kk=0,1). Each phase:
//     8 ds_read (4 af + 4 bf, R3's proven 0-conflict swizzle)
//     3 gload_lds (stage tile tau+2, triple buffer)
//     s_barrier; lgkmcnt(0); sched_barrier(0)
//     setprio(1); 16 reg-only MFMA; setprio(0)
//     s_barrier
//   vmcnt(6) ONCE per K-tile, at end of phase 1 BEFORE its closing barrier
//   (drains tile tau+1's 6 chunks, issued a full tile earlier; never 0).
//   RAW: vmcnt(6)+barrier publishes staged buffer to all waves.
//   WAR: each wave's lgkmcnt(0) precedes the closing barrier, so all reads
//   of buf (tau-1)%3 completed before any tau-phase stage targets it.
// ---------------------------------------------------------------------------
__global__ __launch_bounds__(512, 2) void gemm_bf16(
    const unsigned short* __restrict__ A,
    const unsigned short* __restrict__ Bt,
    const float* __restrict__ bias,
    float* __restrict__ C) {
    __shared__ unsigned short sA[3][BM * BK];  // 3 x 16 KiB
    __shared__ unsigned short sB[3][BN * BK];  // 3 x 32 KiB

    const int t    = threadIdx.x;
    const int lane = t & 63;
    const int wave = t >> 6;
    const int wm   = wave >> 2;  // 0..1
    const int wn   = wave & 3;   // 0..3
    const int lrow = lane & 15;
    const int lhi  = lane >> 4;

    // T1: XCD-aware swizzle (256 WGs, %8==0 -> bijective)
    const int wg  = blockIdx.x;
    const int swz = (wg & 7) * 32 + (wg >> 3);
    const int m0  = (swz >> 4) * BM;
    const int n0  = (swz & 15) * BN;

    // ---- loop-invariant staging pointers (inverse-swizzled global source) ----
    const int rowc = t >> 3;                    // 0..63
    const int lc   = (t & 7) ^ (rowc & 7);      // swizzled k-slot
    const unsigned short* gA0 = A  + (size_t)(m0 + rowc) * K_DIM + lc * 8;
    const unsigned short* gA1 = gA0 + (size_t)64  * K_DIM;   // rows 64..127
    const unsigned short* gB0 = Bt + (size_t)(n0 + rowc) * K_DIM + lc * 8;
    const unsigned short* gB1 = gB0 + (size_t)64  * K_DIM;
    const unsigned short* gB2 = gB0 + (size_t)128 * K_DIM;
    const unsigned short* gB3 = gB0 + (size_t)192 * K_DIM;
    const int dA0 = t * 16, dA1 = t * 16 + 8192;
    const int dB0 = t * 16, dB1 = t * 16 + 8192,
              dB2 = t * 16 + 16384, dB3 = t * 16 + 24576;

    f32x4 acc[4][4];
#pragma unroll
    for (int i = 0; i < 4; ++i)
#pragma unroll
        for (int j = 0; j < 4; ++j) acc[i][j] = (f32x4)0.0f;

    const int NT = K_DIM / BK;  // 64

    // prologue: tiles 0 and 1 fully staged, then publish tile 0
    {
        char* wA = (char*)sA[0]; char* wB = (char*)sB[0];
        gload_lds16(gA0, wA + dA0); gload_lds16(gA1, wA + dA1);
        gload_lds16(gB0, wB + dB0); gload_lds16(gB1, wB + dB1);
        gload_lds16(gB2, wB + dB2); gload_lds16(gB3, wB + dB3);
        wA = (char*)sA[1]; wB = (char*)sB[1];
        gload_lds16(gA0 + BK, wA + dA0); gload_lds16(gA1 + BK, wA + dA1);
        gload_lds16(gB0 + BK, wB + dB0); gload_lds16(gB1 + BK, wB + dB1);
        gload_lds16(gB2 + BK, wB + dB2); gload_lds16(gB3 + BK, wB + dB3);
    }
    asm volatile("s_waitcnt vmcnt(6)" ::: "memory");
    __builtin_amdgcn_s_barrier();

    // per-thread fragment offsets (row&7 == lrow&7 since other terms are x8)
    const int rowOffA = (wm * 64 + lrow) * 128;  // bytes; + mi*2048
    const int rowOffB = (wn * 64 + lrow) * 128;  // bytes; + nj*2048
    const int s0 = ((0 * 4 + lhi) ^ (lrow & 7)) * 16;  // kk=0 slot bytes
    const int s1 = ((1 * 4 + lhi) ^ (lrow & 7)) * 16;  // kk=1 slot bytes

    int bufC = 0, bufS = 2;
    for (int tau = 0; tau < NT; ++tau) {
        const size_t koff = (size_t)((tau + 2 < NT) ? tau + 2 : NT - 1) * BK;
        const char* bA = (const char*)sA[bufC];
        const char* bB = (const char*)sB[bufC];
        char* wA = (char*)sA[bufS];
        char* wB = (char*)sB[bufS];

        // ================= phase 0: kk = 0 =================
        {
            bf16x8 af[4], bf[4];
#pragma unroll
            for (int mi = 0; mi < 4; ++mi)
                af[mi] = *(const bf16x8*)(bA + rowOffA + mi * 2048 + s0);
#pragma unroll
            for (int nj = 0; nj < 4; ++nj)
                bf[nj] = *(const bf16x8*)(bB + rowOffB + nj * 2048 + s0);

            gload_lds16(gA0 + koff, wA + dA0);
            gload_lds16(gA1 + koff, wA + dA1);
            gload_lds16(gB0 + koff, wB + dB0);

            __builtin_amdgcn_s_barrier();
            asm volatile("s_waitcnt lgkmcnt(0)" ::: "memory");
            __builtin_amdgcn_sched_barrier(0);

            __builtin_amdgcn_s_setprio(1);
#pragma unroll
            for (int mi = 0; mi < 4; ++mi)
#pragma unroll
                for (int nj = 0; nj < 4; ++nj)
                    acc[mi][nj] = __builtin_amdgcn_mfma_f32_16x16x32_bf16(
                        af[mi], bf[nj], acc[mi][nj], 0, 0, 0);
            __builtin_amdgcn_s_setprio(0);
            __builtin_amdgcn_s_barrier();
        }

        // ================= phase 1: kk = 1 =================
        {
            bf16x8 af[4], bf[4];
#pragma unroll
            for (int mi = 0; mi < 4; ++mi)
                af[mi] = *(const bf16x8*)(bA + rowOffA + mi * 2048 + s1);
#pragma unroll
            for (int nj = 0; nj < 4; ++nj)
                bf[nj] = *(const bf16x8*)(bB + rowOffB + nj * 2048 + s1);

            gload_lds16(gB1 + koff, wB + dB1);
            gload_lds16(gB2 + koff, wB + dB2);
            gload_lds16(gB3 + koff, wB + dB3);

            __builtin_amdgcn_s_barrier();
            asm volatile("s_waitcnt lgkmcnt(0)" ::: "memory");
            __builtin_amdgcn_sched_barrier(0);

            __builtin_amdgcn_s_setprio(1);
#pragma unroll
            for (int mi = 0; mi < 4; ++mi)
#pragma unroll
                for (int nj = 0; nj < 4; ++nj)
                    acc[mi][nj] = __builtin_amdgcn_mfma_f32_16x16x32_bf16(
                        af[mi], bf[nj], acc[mi][nj], 0, 0, 0);
            __builtin_amdgcn_s_setprio(0);

            // once per K-tile: publish tile tau+1 (its 6 chunks are the
            // oldest outstanding); closing barrier makes it block-wide.
            asm volatile("s_waitcnt vmcnt(6)" ::: "memory");
            __builtin_amdgcn_s_barrier();
        }

        bufC = (bufC == 2) ? 0 : bufC + 1;
        bufS = (bufS == 2) ? 0 : bufS + 1;
    }

    // epilogue: C/D layout col=lane&15, row=(lane>>4)*4+reg
#pragma unroll
    for (int nj = 0; nj < 4; ++nj) {
        int col  = n0 + wn * 64 + nj * 16 + lrow;
        float bv = bias[col];
#pragma unroll
        for (int mi = 0; mi < 4; ++mi) {
            int rbase = m0 + wm * 64 + mi * 16 + lhi * 4;
#pragma unroll
            for (int r = 0; r < 4; ++r) {
                C[(size_t)(rbase + r) * N_DIM + col] = acc[mi][nj][r] + bv;
            }
        }
    }
}

// ---------------------------------------------------------------------------
extern "C" void kernel_launch(void* const* d_in, const int* in_sizes, int n_in,
                              void* d_out, int out_size, void* d_ws, size_t ws_size,
                              hipStream_t stream) {
    const float* x    = (const float*)d_in[0];
    const float* w    = (const float*)d_in[1];
    const float* bias = (const float*)d_in[2];
    float* out        = (float*)d_out;

    unsigned short* xb = (unsigned short*)d_ws;
    unsigned short* wt = (unsigned short*)((char*)d_ws +
                          (size_t)M_DIM * K_DIM * sizeof(unsigned short));

    convert_x_kernel<<<2048, 256, 0, stream>>>(x, xb, M_DIM * K_DIM / 8);

    dim3 tgrid(N_DIM / 64, K_DIM / 64);
    transpose_convert_w<<<tgrid, 256, 0, stream>>>(w, wt);

    dim3 ggrid((M_DIM / BM) * (N_DIM / BN));
    gemm_bf16<<<ggrid, 512, 0, stream>>>(xb, wt, bias, out);
}